// Round 7
// baseline (301.766 us; speedup 1.0000x reference)
//
#include <hip/hip_runtime.h>

#define N_NODES 50000
#define N_EDGES 1600000
#define IN_DIM 6
#define H 64

#define NBUCKET 196            // dst >> 8  (256 nodes per bucket)
#define BCAP 9216              // bucket capacity: mean 8163, sd ~90 -> +11.6 sd

#define L2PAD 72               // padded LDS row stride (bf16) = 144B
#define ZPLANE ((size_t)(N_NODES + 1) * 32)   // bf16 elems per feature plane

#define K1GRID 512

// bf16 helpers (storage-only; all math in fp32)
__device__ __forceinline__ float bf2f(unsigned short u) {
    return __uint_as_float(((unsigned int)u) << 16);
}
__device__ __forceinline__ unsigned short f2bf(float f) {
    unsigned int u = __float_as_uint(f);
    u += 0x7fffu + ((u >> 16) & 1u);   // round-to-nearest-even
    return (unsigned short)(u >> 16);
}

// ---------------------------------------------------------------------------
// K1: per-node degree count via global atomics (deg[] is 200KB, L2-resident,
// ~32 hits/counter -> low contention). Also packs x into xp (32B rows, plus
// zero row), and block K1GRID-1 does W2 transpose prep + z dummy rows.
// Reads ONLY the dst half of ei (6.4 MB).
// ---------------------------------------------------------------------------
__global__ __launch_bounds__(1024) void count_deg(
        const int* __restrict__ ei,
        const float* __restrict__ x,
        int* __restrict__ deg,
        const float* __restrict__ W2l,
        const float* __restrict__ W2r,
        unsigned short* __restrict__ Wlt,
        unsigned short* __restrict__ Wrt,
        unsigned short* __restrict__ z,
        float* __restrict__ xp) {
    int t = threadIdx.x;
    int tid = blockIdx.x * 1024 + t;
    // x -> xp pack (+ zero row at index N_NODES)
    if (tid < N_NODES) {
        const float2* xr = (const float2*)(x + (size_t)tid * IN_DIM);
        float2 p0 = xr[0], p1 = xr[1], p2 = xr[2];
        float4* xw = (float4*)(xp + ((size_t)tid << 3));
        xw[0] = make_float4(p0.x, p0.y, p1.x, p1.y);
        xw[1] = make_float4(p2.x, p2.y, 0.f, 0.f);
    } else if (tid == N_NODES) {
        float4* xw = (float4*)(xp + ((size_t)N_NODES << 3));
        xw[0] = make_float4(0.f, 0.f, 0.f, 0.f);
        xw[1] = make_float4(0.f, 0.f, 0.f, 0.f);
    }
    if (blockIdx.x == K1GRID - 1) {            // w2prep + z dummy rows
        for (int i = t; i < H * H; i += 1024) {
            int k = i >> 6, f = i & 63;
            Wlt[f * H + k] = f2bf(W2l[i]);
            Wrt[f * H + k] = f2bf(W2r[i]);
        }
        if (t < 64)
            z[(size_t)(t >> 5) * ZPLANE + (size_t)N_NODES * 32 + (t & 31)] = 0;
    }
    // degree histogram (dst half only)
    const int4* d4 = (const int4*)(ei + N_EDGES);
    if (tid < N_EDGES / 4) {
        int4 dv = d4[tid];
        atomicAdd(&deg[dv.x], 1);
        atomicAdd(&deg[dv.y], 1);
        atomicAdd(&deg[dv.z], 1);
        atomicAdd(&deg[dv.w], 1);
    }
}

// ---------------------------------------------------------------------------
// K2: per-bucket node scan. Block b scans deg[b*256 .. +256) (4-wave shfl
// scan), writes rowpair (absolute esrc ranges at fixed base b*BCAP) and cur
// (running write cursor for K3). Bucket totals ~8163 +- 90 << BCAP.
// ---------------------------------------------------------------------------
__global__ __launch_bounds__(256) void node_scan(
        const int* __restrict__ deg,
        int2* __restrict__ rowpair,
        int* __restrict__ cur) {
    __shared__ int wsum[4];
    int t = threadIdx.x;
    int lane = t & 63, w = t >> 6;
    int b = blockIdx.x;
    int base = b << 8;
    int nn = min(256, N_NODES - base);
    int v = (t < nn) ? deg[base + t] : 0;
    int s = v;
#pragma unroll
    for (int off = 1; off < 64; off <<= 1) {
        int u = __shfl_up(s, off);
        if (lane >= off) s += u;
    }
    if (lane == 63) wsum[w] = s;
    __syncthreads();
    int woff = 0;
    for (int k = 0; k < w; k++) woff += wsum[k];
    int excl = s - v + woff;                   // bucket-local exclusive prefix
    if (t < nn) {
        int abs0 = b * BCAP + excl;
        rowpair[base + t] = make_int2(abs0, abs0 + v);
        cur[base + t] = abs0;
    }
}

// ---------------------------------------------------------------------------
// K3: edge placement. pos = atomicAdd(cur[dst]); esrc[pos] = src. One pass,
// no LDS staging, no ebin round-trip. Order within a node is nondeterministic
// (benign: feeds an fp32 mean).
// ---------------------------------------------------------------------------
__global__ __launch_bounds__(1024) void place_edges(
        const int* __restrict__ ei,
        int* __restrict__ cur,
        unsigned short* __restrict__ esrc) {
    int tid = blockIdx.x * 1024 + threadIdx.x;
    if (tid >= N_EDGES / 4) return;
    const int4* s4 = (const int4*)ei;
    const int4* d4 = (const int4*)(ei + N_EDGES);
    int4 sv = s4[tid];
    int4 dv = d4[tid];
    int p0 = atomicAdd(&cur[dv.x], 1); esrc[p0] = (unsigned short)sv.x;
    int p1 = atomicAdd(&cur[dv.y], 1); esrc[p1] = (unsigned short)sv.y;
    int p2 = atomicAdd(&cur[dv.z], 1); esrc[p2] = (unsigned short)sv.z;
    int p3 = atomicAdd(&cur[dv.w], 1); esrc[p3] = (unsigned short)sv.w;
}

// ---------------------------------------------------------------------------
// K4: sort-free layer 1. 512 thr / 8 waves / 32 nodes per block (grid 1563).
// Wave w -> nodes w*4..w*4+3. Gather xp rows (32B: 4 lanes x 8B -> 16 edges
// per wave-instr; xp = 1.6MB fully L2-resident). Then feat-per-thread linear
// (weights in regs), z written as two feature planes. Tiny LDS -> 4 blk/CU.
// ---------------------------------------------------------------------------
__global__ __launch_bounds__(512) void layer1_ns(
        const float* __restrict__ xp,
        const int2* __restrict__ rowpair,
        const unsigned short* __restrict__ esrc,
        const float* __restrict__ W1l,
        const float* __restrict__ b1,
        const float* __restrict__ W1r,
        unsigned short* __restrict__ z) {
    __shared__ float smx[32 * 16];             // mean 0..7, self 8..15 (f32)
    __shared__ float sW1l[IN_DIM * H];
    __shared__ float sW1r[IN_DIM * H];

    int t = threadIdx.x;
    int w = t >> 6, lane = t & 63;
    int g16 = lane >> 2, l4 = lane & 3;        // 4 lanes per 32B row
    int n0 = blockIdx.x * 32;
    int ln0 = w * 4;

    if (t < IN_DIM * H) { sW1l[t] = W1l[t]; sW1r[t] = W1r[t]; }
    // self rows (8 floats incl pads)
    if (t < 256) {
        int node = t >> 3, k = t & 7;
        int n = n0 + node;
        smx[node * 16 + 8 + k] = (n < N_NODES) ? xp[((size_t)n << 3) + k] : 0.f;
    }

    // ---- gather: wave w -> nodes ln0..ln0+3, one node at a time ----
    for (int j = 0; j < 4; j++) {
        int n = n0 + ln0 + j;
        int r0 = 0, r1 = 0;
        if (n < N_NODES) { int2 rp = rowpair[n]; r0 = rp.x; r1 = rp.y; }
        int deg = r1 - r0;
        int ii = r0 + lane;
        int idx = (ii < r1) ? (int)esrc[ii] : N_NODES;     // zero row pad
        float a0 = 0.f, a1 = 0.f;
#pragma unroll
        for (int tt = 0; tt < 4; tt++) {
            if (tt * 16 >= deg) break;                     // wave-uniform
            int s = __shfl(idx, tt * 16 + g16);
            const float2* xr = (const float2*)(xp + ((size_t)s << 3) + l4 * 2);
            float2 v = xr[0];
            a0 += v.x; a1 += v.y;
        }
        if (deg > 64) {                                    // rare fallback
            for (int eb = r0 + 64; eb < r1; eb += 64) {
                int ii2 = eb + lane;
                int idx2 = (ii2 < r1) ? (int)esrc[ii2] : N_NODES;
                int rem = r1 - eb;
#pragma unroll
                for (int tt = 0; tt < 4; tt++) {
                    if (tt * 16 >= rem) break;             // wave-uniform
                    int s = __shfl(idx2, tt * 16 + g16);
                    const float2* xr = (const float2*)(xp + ((size_t)s << 3) + l4 * 2);
                    float2 v = xr[0];
                    a0 += v.x; a1 += v.y;
                }
            }
        }
#pragma unroll
        for (int off = 4; off < 64; off <<= 1) {           // reduce 16 groups
            a0 += __shfl_xor(a0, off);
            a1 += __shfl_xor(a1, off);
        }
        float inv = 1.0f / fmaxf((float)deg, 1.0f);
        if (g16 == 0) {                                    // lanes 0..3
            smx[(ln0 + j) * 16 + l4 * 2 + 0] = a0 * inv;
            smx[(ln0 + j) * 16 + l4 * 2 + 1] = a1 * inv;
        }
    }
    __syncthreads();

    // ---- linear: feat-per-thread, weights in registers ----
    int feat = t & 63, ng = t >> 6;             // 8 node-groups
    float wl[IN_DIM], wr[IN_DIM];
#pragma unroll
    for (int k = 0; k < IN_DIM; k++) { wl[k] = sW1l[k * H + feat]; wr[k] = sW1r[k * H + feat]; }
    float bias = b1[feat];
    int plane = feat >> 5, f5 = feat & 31;      // z plane split
    unsigned short* zw = z + (size_t)plane * ZPLANE + f5;
    for (int nb = ng; nb < 32; nb += 8) {
        if (n0 + nb >= N_NODES) break;
        const float4* row = (const float4*)&smx[nb * 16];  // broadcast reads
        float4 r0 = row[0], r1 = row[1], r2 = row[2], r3 = row[3];
        float acc = bias;
        acc += r0.x * wl[0] + r0.y * wl[1] + r0.z * wl[2]
             + r0.w * wl[3] + r1.x * wl[4] + r1.y * wl[5];
        acc += r2.x * wr[0] + r2.y * wr[1] + r2.z * wr[2]
             + r2.w * wr[3] + r3.x * wr[4] + r3.y * wr[5];
        zw[(size_t)(n0 + nb) * 32] = f2bf(fmaxf(acc, 0.0f));
    }
}

// ---------------------------------------------------------------------------
// K5: layer 2, MFMA epilogue — round-3 structure VERBATIM (proven 48.2us,
// FETCH = per-XCD compulsory ~52MB). Two-pass gather over z feature planes
// (3.2MB each, L2-resident); one node's rows in flight at a time.
// ---------------------------------------------------------------------------
__global__ __launch_bounds__(512) void layer2_mfma(
        const unsigned short* __restrict__ zin,
        const int2* __restrict__ rowpair,
        const unsigned short* __restrict__ esrc,
        const unsigned short* __restrict__ Wlt,
        const float* __restrict__ b2,
        const unsigned short* __restrict__ Wrt,
        float* __restrict__ out) {
    typedef short bf16x8 __attribute__((ext_vector_type(8)));
    typedef float f32x4 __attribute__((ext_vector_type(4)));
    __shared__ __attribute__((aligned(16))) unsigned short smean[32 * L2PAD];
    __shared__ __attribute__((aligned(16))) unsigned short szl[32 * L2PAD];
    __shared__ __attribute__((aligned(16))) unsigned short sWl[64 * L2PAD];
    __shared__ __attribute__((aligned(16))) unsigned short sWr[64 * L2PAD];

    int t = threadIdx.x;
    int w = t >> 6, lane = t & 63;
    int g8 = lane >> 3, l8 = lane & 7;          // gather: 8 lanes per 64B row
    int n0 = blockIdx.x * 32;

    // stage pre-transposed bf16 weights (k-consecutive: conflict-free)
    {
        const ushort4* wl4 = (const ushort4*)Wlt;
        const ushort4* wr4 = (const ushort4*)Wrt;
        for (int qi = t; qi < H * H / 4; qi += 512) {
            int f = qi >> 4, kq = qi & 15;
            *(ushort4*)&sWl[f * L2PAD + kq * 4] = wl4[qi];
            *(ushort4*)&sWr[f * L2PAD + kq * 4] = wr4[qi];
        }
    }

    // ---- gather: two passes (one z plane each), wave w -> nodes w*4..w*4+3 --
#pragma unroll 1
    for (int pass = 0; pass < 2; pass++) {
        const unsigned short* zp = zin + (size_t)pass * ZPLANE;
        for (int q = 0; q < 4; q++) {
            int ln = w * 4 + q;
            int n = n0 + ln;
            bool valid = (n < N_NODES);
            int r0 = 0, r1 = 0;
            if (valid) { int2 rp = rowpair[n]; r0 = rp.x; r1 = rp.y; }
            float4 acc = make_float4(0.f, 0.f, 0.f, 0.f);
            for (int base = r0; base < r1; base += 64) {
                int ii = base + lane;
                int idx = (ii < r1) ? (int)esrc[ii] : N_NODES;   // zero row
                int rem = r1 - base;                             // wave-uniform
                // edges 0..31: 4 loads in flight per lane
#pragma unroll
                for (int tt = 0; tt < 4; tt++) {
                    int s = __shfl(idx, tt * 8 + g8);
                    const ushort4* zr = (const ushort4*)(zp + (size_t)s * 32);
                    ushort4 vv = zr[l8];
                    acc.x += bf2f(vv.x); acc.y += bf2f(vv.y);
                    acc.z += bf2f(vv.z); acc.w += bf2f(vv.w);
                }
                if (rem > 32) {                                  // wave-uniform
#pragma unroll
                    for (int tt = 4; tt < 8; tt++) {
                        int s = __shfl(idx, tt * 8 + g8);
                        const ushort4* zr = (const ushort4*)(zp + (size_t)s * 32);
                        ushort4 vv = zr[l8];
                        acc.x += bf2f(vv.x); acc.y += bf2f(vv.y);
                        acc.z += bf2f(vv.z); acc.w += bf2f(vv.w);
                    }
                }
            }
            // reduce over the 8 edge-groups (keep l8)
#pragma unroll
            for (int off = 8; off < 64; off <<= 1) {
                acc.x += __shfl_xor(acc.x, off);
                acc.y += __shfl_xor(acc.y, off);
                acc.z += __shfl_xor(acc.z, off);
                acc.w += __shfl_xor(acc.w, off);
            }
            float inv = 1.0f / fmaxf((float)(r1 - r0), 1.0f);
            if (g8 == 0) {
                ushort4 mb;
                mb.x = f2bf(acc.x * inv); mb.y = f2bf(acc.y * inv);
                mb.z = f2bf(acc.z * inv); mb.w = f2bf(acc.w * inv);
                *(ushort4*)&smean[ln * L2PAD + pass * 32 + l8 * 4] = mb;
            }
            if (pass == 0) {                    // self rows (both planes)
                int nz = valid ? n : N_NODES;   // zero row for pad
                szl[ln * L2PAD + lane] =
                    zin[(size_t)(lane >> 5) * ZPLANE + (size_t)nz * 32 + (lane & 31)];
            }
        }
    }
    __syncthreads();

    // ---- MFMA phase: wave w -> nodes [16*(w>>2), +16) x feats [16*(w&3), +16)
    int g = lane >> 4, lg = lane & 15;
    int nb = w >> 2, fb = w & 3;
    f32x4 acc = {0.f, 0.f, 0.f, 0.f};
#pragma unroll
    for (int ks = 0; ks < 2; ks++) {
        int ko = ks * 32 + g * 8;
        bf16x8 aM = *(const bf16x8*)&smean[(nb * 16 + lg) * L2PAD + ko];
        bf16x8 aZ = *(const bf16x8*)&szl[(nb * 16 + lg) * L2PAD + ko];
        bf16x8 bL = *(const bf16x8*)&sWl[(fb * 16 + lg) * L2PAD + ko];
        bf16x8 bR = *(const bf16x8*)&sWr[(fb * 16 + lg) * L2PAD + ko];
        acc = __builtin_amdgcn_mfma_f32_16x16x32_bf16(aM, bL, acc, 0, 0, 0);
        acc = __builtin_amdgcn_mfma_f32_16x16x32_bf16(aZ, bR, acc, 0, 0, 0);
    }
    float bias = b2[fb * 16 + lg];
#pragma unroll
    for (int r = 0; r < 4; r++) {
        int node = n0 + nb * 16 + g * 4 + r;
        if (node < N_NODES)
            out[(size_t)node * H + fb * 16 + lg] = acc[r] + bias;
    }
}

// ---------------------------------------------------------------------------
extern "C" void kernel_launch(void* const* d_in, const int* in_sizes, int n_in,
                              void* d_out, int out_size, void* d_ws, size_t ws_size,
                              hipStream_t stream) {
    const float* x   = (const float*)d_in[0];
    const int*   ei  = (const int*)d_in[1];   // [2, N_EDGES] (int32 under jax defaults)
    const float* W1l = (const float*)d_in[2];
    const float* b1  = (const float*)d_in[3];
    const float* W1r = (const float*)d_in[4];
    const float* W2l = (const float*)d_in[5];
    const float* b2  = (const float*)d_in[6];
    const float* W2r = (const float*)d_in[7];
    float* out = (float*)d_out;

    // Workspace layout (16B alignment maintained):
    int* deg = (int*)d_ws;                                // 50016 ints
    int* cur = deg + 50016;                               // 50016 ints
    int2* rowpair = (int2*)(cur + 50016);                 // 50000 int2
    unsigned short* esrc = (unsigned short*)(rowpair + N_NODES);  // 196*9216 u16
    unsigned short* z    = esrc + (size_t)NBUCKET * BCAP; // 2 planes, (N+1)*32 each
    unsigned short* Wlt  = z + 2 * ZPLANE;                // 4096 bf16
    unsigned short* Wrt  = Wlt + H * H;                   // 4096 bf16
    float* xp = (float*)(Wrt + H * H);                    // (N+1)*8 f32

    hipMemsetAsync(deg, 0, 50016 * sizeof(int), stream);

    count_deg<<<K1GRID, 1024, 0, stream>>>(ei, x, deg, W2l, W2r, Wlt, Wrt, z, xp);
    node_scan<<<NBUCKET, 256, 0, stream>>>(deg, rowpair, cur);
    place_edges<<<(N_EDGES / 4 + 1023) / 1024, 1024, 0, stream>>>(ei, cur, esrc);
    layer1_ns<<<(N_NODES + 31) / 32, 512, 0, stream>>>(xp, rowpair, esrc,
                                                       W1l, b1, W1r, z);
    layer2_mfma<<<(N_NODES + 31) / 32, 512, 0, stream>>>(z, rowpair, esrc,
                                                         Wlt, b2, Wrt, out);
}

// Round 8
// 172.504 us; speedup vs baseline: 1.7493x; 1.7493x over previous
//
#include <hip/hip_runtime.h>

#define N_NODES 50000
#define N_EDGES 1600000
#define IN_DIM 6
#define H 64

#define NBUCKET 196            // dst >> 8  (256 nodes per bucket)
#define NBLK 196               // edge chunks
#define EPB 8192               // edges per chunk (196*8192 >= 1.6M)
#define BCAP 9216              // bucket capacity: mean 8163, sd ~90 -> +11.6 sd

#define L2PAD 72               // padded LDS row stride (bf16) = 144B
#define ZPLANE ((size_t)(N_NODES + 1) * 32)   // bf16 elems per feature plane

// bf16 helpers (storage-only; all math in fp32)
__device__ __forceinline__ float bf2f(unsigned short u) {
    return __uint_as_float(((unsigned int)u) << 16);
}
__device__ __forceinline__ unsigned short f2bf(float f) {
    unsigned int u = __float_as_uint(f);
    u += 0x7fffu + ((u >> 16) & 1u);   // round-to-nearest-even
    return (unsigned short)(u >> 16);
}

// ---------------------------------------------------------------------------
// Pass A (fused): stage edges in LDS, LDS histogram, reserve bucket ranges
// via ONE global atomicAdd per (block,bucket), scatter from LDS.
// (r7 lesson: scattered u16 global stores write-allocate 64B lines -> 114MB
// amplification; this LDS-staged layout keeps ebin/esrc writes in ~168B runs.)
// Also packs x into xp (32B rows); block NBLK does W2 transpose prep and
// zeroes the dummy row of BOTH z feature planes.
// ---------------------------------------------------------------------------
__global__ __launch_bounds__(1024) void scatter_bucketed(
        const int* __restrict__ ei,
        const float* __restrict__ x,
        int* __restrict__ gcur,
        unsigned int* __restrict__ ebin,
        const float* __restrict__ W2l,
        const float* __restrict__ W2r,
        unsigned short* __restrict__ Wlt,
        unsigned short* __restrict__ Wrt,
        unsigned short* __restrict__ z,
        float* __restrict__ xp) {
    int t = threadIdx.x;
    // x -> xp pack: first 49 blocks cover 50000 nodes
    int gid = blockIdx.x * 1024 + t;
    if (gid < N_NODES) {
        const float2* xr = (const float2*)(x + (size_t)gid * IN_DIM);
        float2 p0 = xr[0], p1 = xr[1], p2 = xr[2];
        float4* xw = (float4*)(xp + ((size_t)gid << 3));
        xw[0] = make_float4(p0.x, p0.y, p1.x, p1.y);
        xw[1] = make_float4(p2.x, p2.y, 0.f, 0.f);
    }
    if (blockIdx.x == NBLK) {                  // w2prep + z zero-row block
        for (int i = t; i < H * H; i += 1024) {
            int k = i >> 6, f = i & 63;
            Wlt[f * H + k] = f2bf(W2l[i]);
            Wrt[f * H + k] = f2bf(W2r[i]);
        }
        if (t < 64)                             // dummy row in both planes
            z[(size_t)(t >> 5) * ZPLANE + (size_t)N_NODES * 32 + (t & 31)] = 0;
        return;
    }
    __shared__ unsigned int sedge[EPB];        // 32 KB staged edges
    __shared__ int hist[NBUCKET];
    __shared__ int cur[NBUCKET];
    if (t < NBUCKET) hist[t] = 0;
    __syncthreads();
    int e0 = blockIdx.x * EPB;
    int cnt = min(EPB, N_EDGES - e0);          // multiple of 4
    const int4* s4 = (const int4*)(ei + e0);
    const int4* d4 = (const int4*)(ei + N_EDGES + e0);
    for (int k = t; k * 4 < cnt; k += 1024) {
        int4 sv = s4[k];
        int4 dv = d4[k];
        sedge[k * 4 + 0] = ((unsigned)sv.x << 16) | (unsigned)dv.x;
        sedge[k * 4 + 1] = ((unsigned)sv.y << 16) | (unsigned)dv.y;
        sedge[k * 4 + 2] = ((unsigned)sv.z << 16) | (unsigned)dv.z;
        sedge[k * 4 + 3] = ((unsigned)sv.w << 16) | (unsigned)dv.w;
        atomicAdd(&hist[dv.x >> 8], 1);
        atomicAdd(&hist[dv.y >> 8], 1);
        atomicAdd(&hist[dv.z >> 8], 1);
        atomicAdd(&hist[dv.w >> 8], 1);
    }
    __syncthreads();
    if (t < NBUCKET) cur[t] = atomicAdd(&gcur[t], hist[t]);
    __syncthreads();
    for (int k = t; k * 4 < cnt; k += 1024) {
#pragma unroll
        for (int j = 0; j < 4; j++) {
            unsigned int p = sedge[k * 4 + j];
            int b = (int)(p & 0xffffu) >> 8;
            int pos = atomicAdd(&cur[b], 1);
            if (pos < BCAP) ebin[(size_t)b * BCAP + pos] = p;
        }
    }
}

// ---------------------------------------------------------------------------
// Pass B + Layer 1 fused: one block (1024 thr) per 256-node bucket.
// x-gather 4-way unrolled; z written as two feature planes for the
// L2-resident layer-2 gather.
// ---------------------------------------------------------------------------
__global__ __launch_bounds__(1024) void bucket_layer1(
        const unsigned int* __restrict__ ebin,
        const int* __restrict__ gcur,
        const float* __restrict__ xp,
        const float* __restrict__ W1l,
        const float* __restrict__ b1,
        const float* __restrict__ W1r,
        int2* __restrict__ rowpair,
        unsigned short* __restrict__ esrc,
        unsigned short* __restrict__ z) {
    __shared__ int raw[BCAP];                  // 36864 B (aliased below)
    __shared__ unsigned short ssrc[BCAP];      // 18432 B
    __shared__ int sdeg[256];
    __shared__ int sstart[256];
    __shared__ int scur[256];
    __shared__ int wsum[4];
    __shared__ float sW1l[IN_DIM * H];
    __shared__ float sW1r[IN_DIM * H];
    float* smx   = (float*)raw;                // [256][16]: mean 0..5, self 6..11
    float* spart = (float*)raw + 4096;         // [3][256][6] partials (q=1..3)

    int t = threadIdx.x;
    int lane = t & 63, w = t >> 6;
    int b = blockIdx.x;
    int base = b << 8;
    int nn = min(256, N_NODES - base);         // last bucket has 80 nodes
    int ebase = b * BCAP;
    int cnt = min(gcur[b], BCAP);

    if (t < 256) sdeg[t] = 0;
    if (t < IN_DIM * H) { sW1l[t] = W1l[t]; sW1r[t] = W1r[t]; }
    for (int i = t; i < cnt; i += 1024) raw[i] = (int)ebin[ebase + i];
    __syncthreads();
    for (int i = t; i < cnt; i += 1024) atomicAdd(&sdeg[raw[i] & 0xff], 1);
    __syncthreads();
    int v = 0, s = 0;
    if (t < 256) {                              // waves 0..3: scan of 256 bins
        v = sdeg[t]; s = v;
#pragma unroll
        for (int off = 1; off < 64; off <<= 1) {
            int u = __shfl_up(s, off);
            if (lane >= off) s += u;
        }
        if (lane == 63) wsum[w] = s;
    }
    __syncthreads();
    if (t < 256) {
        int woff = 0;
        for (int k = 0; k < w; k++) woff += wsum[k];
        int excl = s - v + woff;                // bucket-local exclusive prefix
        sstart[t] = excl;
        scur[t] = excl;
        if (t < nn) rowpair[base + t] = make_int2(ebase + excl, ebase + excl + v);
    }
    __syncthreads();
    for (int i = t; i < cnt; i += 1024) {       // in-LDS scatter (sort)
        int p = raw[i];
        int pos = atomicAdd(&scur[p & 0xff], 1);
        ssrc[pos] = (unsigned short)((unsigned)p >> 16);
    }
    __syncthreads();
    // raw[] dead from here on: smx/spart alias it.
    for (int i = t; i < cnt; i += 1024)         // coalesced esrc write (layer2)
        esrc[ebase + i] = ssrc[i];
    for (int i = t; i < nn * 8; i += 1024) {    // stage self rows from xp
        int node = i >> 3, k = i & 7;
        if (k < 6) smx[node * 16 + 6 + k] = xp[(size_t)(base + node) * 8 + k];
    }

    // ---- layer-1 gather: 4 threads/node, 4-way unrolled (8 loads in flight) --
    int node = t & 255, q = t >> 8;             // q in 0..3
    float a0 = 0.f, a1 = 0.f, a2 = 0.f, a3 = 0.f, a4 = 0.f, a5 = 0.f;
    int deg = 0, st = 0;
    if (node < nn) { deg = sdeg[node]; st = sstart[node]; }
    int e = st + q, end = st + deg;
    while (e + 12 < end) {                      // 4 edges per iter (stride 4)
        float4 P[8];
#pragma unroll
        for (int u = 0; u < 4; u++) {
            int src = ssrc[e + u * 4];
            const float4* xs = (const float4*)(xp + ((size_t)src << 3));
            P[2 * u] = xs[0]; P[2 * u + 1] = xs[1];
        }
#pragma unroll
        for (int u = 0; u < 4; u++) {
            a0 += P[2 * u].x; a1 += P[2 * u].y; a2 += P[2 * u].z;
            a3 += P[2 * u].w; a4 += P[2 * u + 1].x; a5 += P[2 * u + 1].y;
        }
        e += 16;
    }
    while (e < end) {                           // tail, order preserved
        int src = ssrc[e];
        const float4* xs = (const float4*)(xp + ((size_t)src << 3));
        float4 p0 = xs[0], p1 = xs[1];
        a0 += p0.x; a1 += p0.y; a2 += p0.z;
        a3 += p0.w; a4 += p1.x; a5 += p1.y;
        e += 4;
    }
    if (q > 0 && node < nn) {
        float* sp = &spart[(q - 1) * (256 * 6) + node * 6];
        sp[0] = a0; sp[1] = a1; sp[2] = a2; sp[3] = a3; sp[4] = a4; sp[5] = a5;
    }
    __syncthreads();
    if (q == 0 && node < nn) {
        float inv = 1.0f / fmaxf((float)deg, 1.0f);
        const float* p1p = &spart[0 * (256 * 6) + node * 6];
        const float* p2p = &spart[1 * (256 * 6) + node * 6];
        const float* p3p = &spart[2 * (256 * 6) + node * 6];
        smx[node * 16 + 0] = (a0 + p1p[0] + p2p[0] + p3p[0]) * inv;
        smx[node * 16 + 1] = (a1 + p1p[1] + p2p[1] + p3p[1]) * inv;
        smx[node * 16 + 2] = (a2 + p1p[2] + p2p[2] + p3p[2]) * inv;
        smx[node * 16 + 3] = (a3 + p1p[3] + p2p[3] + p3p[3]) * inv;
        smx[node * 16 + 4] = (a4 + p1p[4] + p2p[4] + p3p[4]) * inv;
        smx[node * 16 + 5] = (a5 + p1p[5] + p2p[5] + p3p[5]) * inv;
    }
    __syncthreads();

    // ---- layer-1 linear: feat-per-thread, weights in registers ----
    int feat = t & 63, ng = t >> 6;             // 16 node-groups
    float wl[IN_DIM], wr[IN_DIM];
#pragma unroll
    for (int k = 0; k < IN_DIM; k++) { wl[k] = sW1l[k * H + feat]; wr[k] = sW1r[k * H + feat]; }
    float bias = b1[feat];
    int plane = feat >> 5, f5 = feat & 31;      // z plane split
    unsigned short* zw = z + (size_t)plane * ZPLANE + f5;
    for (int nb = ng; nb < nn; nb += 16) {
        const float4* row = (const float4*)&smx[nb * 16];  // broadcast reads
        float4 r0 = row[0], r1 = row[1], r2 = row[2];
        float acc = bias;
        acc += r0.x * wl[0] + r0.y * wl[1] + r0.z * wl[2]
             + r0.w * wl[3] + r1.x * wl[4] + r1.y * wl[5];
        acc += r1.z * wr[0] + r1.w * wr[1] + r2.x * wr[2]
             + r2.y * wr[3] + r2.z * wr[4] + r2.w * wr[5];
        zw[(size_t)(base + nb) * 32] = f2bf(fmaxf(acc, 0.0f));
    }
}

// ---------------------------------------------------------------------------
// Layer 2, MFMA epilogue: r3 structure + H0-only predicated prefetch.
// The ISSUED LOAD SET is identical to r3 (per-tt wave-uniform break on the
// node's own rem) -- r6's regression confounds (round-up loads, big buffers)
// removed. Node q+1's first-half loads are in flight while node q's
// accumulate+reduce chain runs. H1 (rem>32) and deg>64 fallback serial, as r3.
// Skipped groups add +0.0f -> bit-identical output to r3.
// ---------------------------------------------------------------------------
__global__ __launch_bounds__(512) void layer2_mfma(
        const unsigned short* __restrict__ zin,
        const int2* __restrict__ rowpair,
        const unsigned short* __restrict__ esrc,
        const unsigned short* __restrict__ Wlt,
        const float* __restrict__ b2,
        const unsigned short* __restrict__ Wrt,
        float* __restrict__ out) {
    typedef short bf16x8 __attribute__((ext_vector_type(8)));
    typedef float f32x4 __attribute__((ext_vector_type(4)));
    __shared__ __attribute__((aligned(16))) unsigned short smean[32 * L2PAD];
    __shared__ __attribute__((aligned(16))) unsigned short szl[32 * L2PAD];
    __shared__ __attribute__((aligned(16))) unsigned short sWl[64 * L2PAD];
    __shared__ __attribute__((aligned(16))) unsigned short sWr[64 * L2PAD];

    int t = threadIdx.x;
    int w = t >> 6, lane = t & 63;
    int g8 = lane >> 3, l8 = lane & 7;          // gather: 8 lanes per 64B row
    int n0 = blockIdx.x * 32;
    int ln0 = w * 4;

    // ---- prolog: per-node ranges + first-64-edge index vectors (regs) ----
    int r0a[4], rem[4], idxv[4];
#pragma unroll
    for (int j = 0; j < 4; j++) {
        int n = n0 + ln0 + j;
        int2 rp = (n < N_NODES) ? rowpair[n] : make_int2(0, 0);
        r0a[j] = rp.x; rem[j] = rp.y - rp.x;
        int ii = rp.x + lane;
        idxv[j] = (ii < rp.y) ? (int)esrc[ii] : N_NODES;   // zero row pad
    }

    // stage pre-transposed bf16 weights (k-consecutive: conflict-free)
    {
        const ushort4* wl4 = (const ushort4*)Wlt;
        const ushort4* wr4 = (const ushort4*)Wrt;
        for (int qi = t; qi < H * H / 4; qi += 512) {
            int f = qi >> 4, kq = qi & 15;
            *(ushort4*)&sWl[f * L2PAD + kq * 4] = wl4[qi];
            *(ushort4*)&sWr[f * L2PAD + kq * 4] = wr4[qi];
        }
    }

    // ISSUE_H0: prefetch first-half groups (<=4 loads), per-tt predicated so
    // the issued load set == r3's. Skipped V[tt] stay unread (ACCUM guards).
#define ISSUE_H0(J, V)                                                     \
    {                                                                      \
        int idx_ = idxv[J];                                                \
        _Pragma("unroll")                                                  \
        for (int tt = 0; tt < 4; tt++) {                                   \
            if (tt * 8 >= rem[J]) break;        /* wave-uniform */         \
            int s_ = __shfl(idx_, tt * 8 + g8);                            \
            V[tt] = *(const ushort4*)(zp + (size_t)s_ * 32 + l8 * 4);      \
        }                                                                  \
    }
    // BODY: accumulate H0 from buffer, serial H1 (rem>32), rare >64 fallback,
    // reduce, store mean; pass 0 additionally stages this node's szl row.
#define BODY(J, V)                                                         \
    {                                                                      \
        float4 ac = make_float4(0.f, 0.f, 0.f, 0.f);                       \
        _Pragma("unroll")                                                  \
        for (int tt = 0; tt < 4; tt++) {                                   \
            if (tt * 8 >= rem[J]) break;        /* wave-uniform */         \
            ac.x += bf2f(V[tt].x); ac.y += bf2f(V[tt].y);                  \
            ac.z += bf2f(V[tt].z); ac.w += bf2f(V[tt].w);                  \
        }                                                                  \
        if (rem[J] > 32) {                      /* H1 serial, as r3 */     \
            int idx_ = idxv[J];                                            \
            _Pragma("unroll")                                              \
            for (int tt = 4; tt < 8; tt++) {                               \
                int s_ = __shfl(idx_, tt * 8 + g8);                        \
                ushort4 vv = *(const ushort4*)(zp + (size_t)s_ * 32 + l8 * 4); \
                ac.x += bf2f(vv.x); ac.y += bf2f(vv.y);                    \
                ac.z += bf2f(vv.z); ac.w += bf2f(vv.w);                    \
            }                                                              \
        }                                                                  \
        if (rem[J] > 64) {                      /* rare fallback */        \
            for (int eb = r0a[J] + 64; eb < r0a[J] + rem[J]; eb += 64) {   \
                int ii2 = eb + lane;                                       \
                int lim = r0a[J] + rem[J];                                 \
                int idx2 = (ii2 < lim) ? (int)esrc[ii2] : N_NODES;         \
                int rm2 = lim - eb;                                        \
                _Pragma("unroll")                                          \
                for (int tt = 0; tt < 8; tt++) {                           \
                    if (tt * 8 >= rm2) break;   /* wave-uniform */         \
                    int s_ = __shfl(idx2, tt * 8 + g8);                    \
                    ushort4 vv = *(const ushort4*)(zp + (size_t)s_ * 32 + l8 * 4); \
                    ac.x += bf2f(vv.x); ac.y += bf2f(vv.y);                \
                    ac.z += bf2f(vv.z); ac.w += bf2f(vv.w);                \
                }                                                          \
            }                                                              \
        }                                                                  \
        _Pragma("unroll")                                                  \
        for (int off = 8; off < 64; off <<= 1) {                           \
            ac.x += __shfl_xor(ac.x, off);                                 \
            ac.y += __shfl_xor(ac.y, off);                                 \
            ac.z += __shfl_xor(ac.z, off);                                 \
            ac.w += __shfl_xor(ac.w, off);                                 \
        }                                                                  \
        float inv_ = 1.0f / fmaxf((float)rem[J], 1.0f);                    \
        if (g8 == 0) {                                                     \
            ushort4 mb;                                                    \
            mb.x = f2bf(ac.x * inv_); mb.y = f2bf(ac.y * inv_);            \
            mb.z = f2bf(ac.z * inv_); mb.w = f2bf(ac.w * inv_);            \
            *(ushort4*)&smean[(ln0 + J) * L2PAD + pass * 32 + l8 * 4] = mb; \
        }                                                                  \
        if (pass == 0) {                        /* stage self row, as r3 */ \
            int n_ = n0 + ln0 + J;                                         \
            int nz_ = (n_ < N_NODES) ? n_ : N_NODES;                       \
            szl[(ln0 + J) * L2PAD + lane] =                                \
                zin[(size_t)(lane >> 5) * ZPLANE + (size_t)nz_ * 32 + (lane & 31)]; \
        }                                                                  \
    }

#pragma unroll 1
    for (int pass = 0; pass < 2; pass++) {
        const unsigned short* zp = zin + (size_t)pass * ZPLANE;
        ushort4 vA[4], vB[4];
        ISSUE_H0(0, vA)
        ISSUE_H0(1, vB)
        BODY(0, vA)
        ISSUE_H0(2, vA)
        BODY(1, vB)
        ISSUE_H0(3, vB)
        BODY(2, vA)
        BODY(3, vB)
    }
#undef ISSUE_H0
#undef BODY
    __syncthreads();

    // ---- MFMA phase: wave w -> nodes [16*(w>>2), +16) x feats [16*(w&3), +16)
    int g = lane >> 4, lg = lane & 15;
    int nb = w >> 2, fb = w & 3;
    f32x4 acc = {0.f, 0.f, 0.f, 0.f};
#pragma unroll
    for (int ks = 0; ks < 2; ks++) {
        int ko = ks * 32 + g * 8;
        bf16x8 aM = *(const bf16x8*)&smean[(nb * 16 + lg) * L2PAD + ko];
        bf16x8 aZ = *(const bf16x8*)&szl[(nb * 16 + lg) * L2PAD + ko];
        bf16x8 bL = *(const bf16x8*)&sWl[(fb * 16 + lg) * L2PAD + ko];
        bf16x8 bR = *(const bf16x8*)&sWr[(fb * 16 + lg) * L2PAD + ko];
        acc = __builtin_amdgcn_mfma_f32_16x16x32_bf16(aM, bL, acc, 0, 0, 0);
        acc = __builtin_amdgcn_mfma_f32_16x16x32_bf16(aZ, bR, acc, 0, 0, 0);
    }
    float bias = b2[fb * 16 + lg];
#pragma unroll
    for (int r = 0; r < 4; r++) {
        int node = n0 + nb * 16 + g * 4 + r;
        if (node < N_NODES)
            out[(size_t)node * H + fb * 16 + lg] = acc[r] + bias;
    }
}

// ---------------------------------------------------------------------------
extern "C" void kernel_launch(void* const* d_in, const int* in_sizes, int n_in,
                              void* d_out, int out_size, void* d_ws, size_t ws_size,
                              hipStream_t stream) {
    const float* x   = (const float*)d_in[0];
    const int*   ei  = (const int*)d_in[1];   // [2, N_EDGES]
    const float* W1l = (const float*)d_in[2];
    const float* b1  = (const float*)d_in[3];
    const float* W1r = (const float*)d_in[4];
    const float* W2l = (const float*)d_in[5];
    const float* b2  = (const float*)d_in[6];
    const float* W2r = (const float*)d_in[7];
    float* out = (float*)d_out;

    // Workspace layout (keeps 16B alignment for ebin/esrc/z/weights):
    int* gcur = (int*)d_ws;                              // 196 (+pad to 208)
    int2* rowpair = (int2*)(gcur + 208);                 // 50000 int2
    unsigned int*   ebin = (unsigned int*)(rowpair + N_NODES);  // 196*9216 u32
    unsigned short* esrc = (unsigned short*)(ebin + (size_t)NBUCKET * BCAP);
    unsigned short* z    = esrc + (size_t)NBUCKET * BCAP;  // 2 planes, (N+1)*32 each
    unsigned short* Wlt  = z + 2 * ZPLANE;                 // 4096 bf16
    unsigned short* Wrt  = Wlt + H * H;                    // 4096 bf16
    float* xp = (float*)(Wrt + H * H);                     // 50000*8 f32

    hipMemsetAsync(gcur, 0, NBUCKET * sizeof(int), stream);

    // CSR build + x pack + layer1 (fused), then layer2
    scatter_bucketed<<<NBLK + 1, 1024, 0, stream>>>(ei, x, gcur, ebin,
                                                    W2l, W2r, Wlt, Wrt, z, xp);
    bucket_layer1<<<NBUCKET, 1024, 0, stream>>>(ebin, gcur, xp, W1l, b1, W1r,
                                                rowpair, esrc, z);
    layer2_mfma<<<(N_NODES + 31) / 32, 512, 0, stream>>>(z, rowpair, esrc,
                                                         Wlt, b2, Wrt, out);
}